// Round 8
// baseline (328.432 us; speedup 1.0000x reference)
//
#include <hip/hip_runtime.h>
#include <math.h>

#define CC   96
#define DIN  192
#define NST  16
#define KDIR 4
#define DTR  6
#define LL   4096
#define BB   4
#define NSEG 128
#define SEGLEN 32
#define XROW 40      // padded x_dbl row: [0..5]=dt_r, [8..23]=B, [24..39]=C

#define SZ_BLD ((long)BB*LL*DIN)    // 3,145,728

__device__ __forceinline__ float sigmoidf_(float x){
    return __builtin_amdgcn_rcpf(1.0f + __expf(-x));
}
__device__ __forceinline__ int whmap(int l){ return ((l & 63) << 6) | (l >> 6); }

// base-2 softplus + decay: dt = ln(1+e^s), E = exp(-dt) = sigmoid(-s)
__device__ __forceinline__ void dt_and_E(float s, float& dt, float& E){
    const float LOG2E = 1.4426950408889634f;
    const float LN2   = 0.6931471805599453f;
    float sn  = s * LOG2E;
    float t   = __builtin_amdgcn_exp2f(-fabsf(sn));   // 2^(-|sn|) in (0,1]
    float opt = 1.0f + t;
    float r   = __builtin_amdgcn_rcpf(opt);
    E  = (s > 0.f) ? t*r : r;
    dt = LN2 * (fmaxf(sn, 0.f) + __builtin_amdgcn_logf(opt));
}
__device__ __forceinline__ void pow_tree(float E, float* En){
    En[0]=E;
    float E2=E*E;        En[1]=E2;
    En[2]=E2*E;  float E4=E2*E2; En[3]=E4;
    En[4]=E4*E;  En[5]=E4*E2;  En[6]=E4*En[2];
    float E8=E4*E4;      En[7]=E8;
    En[8]=E8*E;  En[9]=E8*E2;  En[10]=E8*En[2]; En[11]=E8*E4;
    En[12]=E8*En[4]; En[13]=E8*En[5]; En[14]=E8*En[6]; En[15]=E8*E8;
}
__device__ __forceinline__ void dir_base(int k, int lg0, int& p0, int& stride){
    switch(k & 3){
        case 0:  p0 = lg0;               stride = 1;   break;
        case 1:  p0 = whmap(lg0);        stride = 64;  break;
        case 2:  p0 = LL - 1 - lg0;      stride = -1;  break;
        default: p0 = whmap(LL-1-lg0);   stride = -64; break;
    }
}

// ---------------- Kernel A: LayerNorm + in_proj GEMM (96 -> 384), 2 cols/thread
__global__ __launch_bounds__(192) void kA(const float* __restrict__ x,
        const float* __restrict__ lng, const float* __restrict__ lnb,
        const float* __restrict__ W,   const float* __restrict__ bias,
        float* __restrict__ xi, float* __restrict__ z)
{
    __shared__ float xn[16*96];
    __shared__ float sc1[192], sc2[192];
    __shared__ float mu[16], rs[16];
    int t = threadIdx.x;
    long row0 = (long)blockIdx.x * 16;

    for(int q=t; q<16*96; q+=192) xn[q] = x[row0*96 + q];
    __syncthreads();
    {   // stats: 16 rows x 12 threads, 8 elems each (2 float4 reads)
        int r = t/12, i = t%12;
        float4 v0 = *(const float4*)(&xn[r*96 + i*8]);
        float4 v1 = *(const float4*)(&xn[r*96 + i*8 + 4]);
        float s  = v0.x+v0.y+v0.z+v0.w + v1.x+v1.y+v1.z+v1.w;
        float ss = v0.x*v0.x+v0.y*v0.y+v0.z*v0.z+v0.w*v0.w
                 + v1.x*v1.x+v1.y*v1.y+v1.z*v1.z+v1.w*v1.w;
        sc1[t]=s; sc2[t]=ss;
        __syncthreads();
        if(t<16){
            float S=0.f, SS=0.f;
            for(int j=0;j<12;j++){ S+=sc1[t*12+j]; SS+=sc2[t*12+j]; }
            float m = S*(1.0f/96.0f);
            float var = SS*(1.0f/96.0f) - m*m;
            mu[t]=m; rs[t]=rsqrtf(var + 1e-6f);
        }
        __syncthreads();
    }
    for(int q=t; q<16*96; q+=192){
        int r=q/96, c=q%96;
        xn[q] = (xn[q]-mu[r])*rs[r]*lng[c] + lnb[c];
    }
    __syncthreads();

    // GEMM: thread owns cols t (-> xi) and t+192 (-> z), 16 rows
    float acc0[16], acc1[16];
    #pragma unroll
    for(int r=0;r<16;r++){ acc0[r]=0.f; acc1[r]=0.f; }
    for(int c0=0; c0<96; c0+=4){
        float4 xv[16];
        #pragma unroll
        for(int r=0;r<16;r++) xv[r] = *(const float4*)(&xn[r*96 + c0]);
        #pragma unroll
        for(int j=0;j<4;j++){
            float w0 = W[(c0+j)*384 + t];
            float w1 = W[(c0+j)*384 + t + 192];
            #pragma unroll
            for(int r=0;r<16;r++){
                float xvj = (j==0)?xv[r].x:(j==1)?xv[r].y:(j==2)?xv[r].z:xv[r].w;
                acc0[r] = fmaf(xvj, w0, acc0[r]);
                acc1[r] = fmaf(xvj, w1, acc1[r]);
            }
        }
    }
    float b0 = bias[t], b1 = bias[t+192];
    #pragma unroll
    for(int r=0;r<16;r++){
        xi[(row0+r)*DIN + t] = acc0[r] + b0;
        z [(row0+r)*DIN + t] = acc1[r] + b1;
    }
}

// ---------------- Kernel B: depthwise 3x3 conv (SAME) + bias + SiLU
__global__ __launch_bounds__(256) void kB(const float* __restrict__ xi,
        const float* __restrict__ cw, const float* __restrict__ cb,
        float* __restrict__ xc)
{
    long idx = (long)blockIdx.x*256 + threadIdx.x;
    if(idx >= SZ_BLD) return;
    int d = (int)(idx % DIN);
    long rg = idx / DIN;
    int p = (int)(rg % LL); int b = (int)(rg / LL);
    int h = p >> 6, w = p & 63;
    float acc = 0.f;
    #pragma unroll
    for(int dh=0; dh<3; dh++){
        int hh = h + dh - 1;
        if(hh < 0 || hh >= 64) continue;
        #pragma unroll
        for(int dw=0; dw<3; dw++){
            int ww2 = w + dw - 1;
            if(ww2 < 0 || ww2 >= 64) continue;
            acc = fmaf(xi[((long)b*LL + hh*64 + ww2)*DIN + d], cw[d*9 + dh*3 + dw], acc);
        }
    }
    acc += cb[d];
    xc[idx] = acc * sigmoidf_(acc);
}

// ---------------- Kernel C: x_proj (192 -> 38x4), 2 dirs/thread, 4 rows/thread
// 304 active threads = 4 row-quarters x 76 col-pairs; pair (k,c) & (k+2,c)
__global__ __launch_bounds__(320) void kC(const float* __restrict__ xc,
        const float* __restrict__ xw, float* __restrict__ xdbl)
{
    __shared__ float ls[16*192];
    int t = threadIdx.x;
    long row0 = (long)blockIdx.x * 16;
    int b  = (int)(row0 / LL);
    int p0 = (int)(row0 % LL);
    for(int q=t; q<16*192; q+=320) ls[q] = xc[row0*DIN + q];
    __syncthreads();
    if(t < 304){
        int q4 = t / 76;            // row quarter 0..3
        int j  = t % 76;            // col-pair id
        int k  = j / 38;            // 0 or 1
        int c  = j % 38;
        const float* wr0 = xw + (long)( k      *38 + c)*192;
        const float* wr1 = xw + (long)((k + 2) *38 + c)*192;
        float acc0[4], acc1[4];
        #pragma unroll
        for(int r=0;r<4;r++){ acc0[r]=0.f; acc1[r]=0.f; }
        int rbase = q4*4;
        for(int d=0; d<192; d+=4){
            float4 w0 = *(const float4*)(wr0 + d);
            float4 w1 = *(const float4*)(wr1 + d);
            #pragma unroll
            for(int r=0;r<4;r++){
                float4 lv = *(const float4*)(&ls[(rbase+r)*192 + d]);
                acc0[r] = fmaf(lv.x,w0.x, fmaf(lv.y,w0.y, fmaf(lv.z,w0.z, fmaf(lv.w,w0.w, acc0[r]))));
                acc1[r] = fmaf(lv.x,w1.x, fmaf(lv.y,w1.y, fmaf(lv.z,w1.z, fmaf(lv.w,w1.w, acc1[r]))));
            }
        }
        int cs = (c < 6) ? c : c + 2;   // dt at 0..5, B at 8..23, C at 24..39
        long base0 = (long)(b*KDIR + k)*LL;
        long base2 = (long)(b*KDIR + k + 2)*LL;
        #pragma unroll
        for(int r=0;r<4;r++){
            int p  = p0 + rbase + r;
            int lk = (k==0) ? p : whmap(p);
            xdbl[(base0 + lk)*XROW + cs]            = acc0[r];
            xdbl[(base2 + (LL-1-lk))*XROW + cs]     = acc1[r];
        }
    }
}

// ---------------- Kernel D2: scan pass 1 — segment-local hend + dtsum ONLY
__global__ __launch_bounds__(192) void kD2(const float* __restrict__ xc,
        const float* __restrict__ xdbl, const float* __restrict__ alog,
        const float* __restrict__ dtw,  const float* __restrict__ dtb,
        float* __restrict__ hend, float* __restrict__ dtsum)
{
    __shared__ float rows[SEGLEN*XROW];
    int t = threadIdx.x;
    int blk = blockIdx.x;
    int bk = blk / NSEG, seg = blk % NSEG;
    int b = bk / KDIR, k = bk % KDIR;
    {
        const float* src = xdbl + ((long)bk*LL + seg*SEGLEN)*XROW;
        for(int q=t; q<SEGLEN*XROW; q+=192) rows[q] = src[q];
    }
    int d = t, kd = k*192 + d;
    float a[16]; bool fast = true;
    #pragma unroll
    for(int n=0;n<16;n++){
        a[n] = -__expf(alog[kd*16 + n]);
        fast = fast && (fabsf(a[n] + (float)(n+1)) < 1e-3f);
    }
    float w6[6];
    #pragma unroll
    for(int r=0;r<6;r++) w6[r] = dtw[kd*6 + r];
    float bdt = dtb[kd];

    int lg0 = seg * SEGLEN;
    int p0, stride; dir_base(k, lg0, p0, stride);
    long addr  = ((long)b*LL + p0)*DIN + d;
    long astep = (long)stride*DIN;

    float h[16];
    #pragma unroll
    for(int n=0;n<16;n++) h[n]=0.f;
    float sdt = 0.f;
    __syncthreads();

    float u = xc[addr];
    for(int i=0; i<SEGLEN; i++){
        const float* row = &rows[i*XROW];
        float s = bdt;
        #pragma unroll
        for(int r=0;r<6;r++) s = fmaf(row[r], w6[r], s);
        float dt, E; dt_and_E(s, dt, E);
        sdt += dt;
        float wi = dt * u;
        float unext = 0.f;
        long addrN = addr + astep;
        if(i+1 < SEGLEN) unext = xc[addrN];
        float En[16];
        if(fast){ pow_tree(E, En); }
        else {
            #pragma unroll
            for(int n=0;n<16;n++) En[n] = __expf(dt * a[n]);
        }
        float Bv[16];
        #pragma unroll
        for(int n=0;n<16;n+=4) *(float4*)(Bv+n) = *(const float4*)(row + 8 + n);
        #pragma unroll
        for(int n=0;n<16;n++) h[n] = fmaf(En[n], h[n], wi*Bv[n]);
        addr = addrN; u = unext;
    }
    long hb = (((long)bk*NSEG + seg)*192 + d)*16;
    #pragma unroll
    for(int n=0;n<16;n+=4)
        *(float4*)(&hend[hb+n]) = make_float4(h[n],h[n+1],h[n+2],h[n+3]);
    dtsum[((long)bk*NSEG + seg)*192 + d] = sdt;
}

// ---------------- Kernel E3: inter-segment scan, chunk-parallel + wave-shuffle
__global__ __launch_bounds__(256) void kE3(const float* __restrict__ alog,
        const float* __restrict__ dtsum, float* __restrict__ hx)
{
    int tid = blockIdx.x*256 + threadIdx.x;   // 786432 total
    int c     = tid & 15;                      // chunk id within chain
    int chain = tid >> 4;                      // 49152 chains
    int n  = chain & 15;
    int d  = (chain >> 4) % 192;
    int bk = chain / 3072;
    int k  = bk & 3;
    float an = -__expf(alog[(k*192 + d)*16 + n]);
    long sbase = (long)bk*NSEG*192  + d;          // + seg*192
    long hbase = (long)bk*NSEG*3072 + d*16 + n;   // + seg*3072
    int seg0 = c*8;

    float P[8], he[8];
    #pragma unroll
    for(int i=0;i<8;i++){
        float sd = dtsum[sbase + (long)(seg0+i)*192];
        he[i]    = hx[hbase + (long)(seg0+i)*3072];
        P[i]     = __expf(an * sd);
    }
    float Pc = 1.f, Hc = 0.f;
    #pragma unroll
    for(int i=0;i<8;i++){
        Hc = fmaf(P[i], Hc, he[i]);
        Pc *= P[i];
    }
    #pragma unroll
    for(int dist=1; dist<16; dist<<=1){
        float Pp = __shfl_up(Pc, dist, 16);
        float Hp = __shfl_up(Hc, dist, 16);
        if(c >= dist){
            Hc = fmaf(Pc, Hp, Hc);
            Pc *= Pp;
        }
    }
    float H = __shfl_up(Hc, 1, 16);
    if(c == 0) H = 0.f;
    #pragma unroll
    for(int i=0;i<8;i++){
        hx[hbase + (long)(seg0+i)*3072] = H;
        H = fmaf(P[i], H, he[i]);
    }
}

// ---------------- Kernel F2: scan pass 3 — full scan from Hprev, single ys write
__global__ __launch_bounds__(192) void kF2(const float* __restrict__ xc,
        const float* __restrict__ xdbl, const float* __restrict__ alog,
        const float* __restrict__ dtw,  const float* __restrict__ dtb,
        const float* __restrict__ Ds,   const float* __restrict__ Hprev,
        float* __restrict__ ys0, float* __restrict__ ys123)
{
    __shared__ float rows[SEGLEN*XROW];
    int t = threadIdx.x;
    int blk = blockIdx.x;
    int bk = blk / NSEG, seg = blk % NSEG;
    int b = bk / KDIR, k = bk % KDIR;
    {
        const float* src = xdbl + ((long)bk*LL + seg*SEGLEN)*XROW;
        for(int q=t; q<SEGLEN*XROW; q+=192) rows[q] = src[q];
    }
    int d = t, kd = k*192 + d;
    float a[16]; bool fast = true;
    #pragma unroll
    for(int n=0;n<16;n++){
        a[n] = -__expf(alog[kd*16 + n]);
        fast = fast && (fabsf(a[n] + (float)(n+1)) < 1e-3f);
    }
    float w6[6];
    #pragma unroll
    for(int r=0;r<6;r++) w6[r] = dtw[kd*6 + r];
    float bdt = dtb[kd];
    float Dd  = Ds[kd];
    float h[16];
    long hb = (((long)bk*NSEG + seg)*192 + d)*16;
    #pragma unroll
    for(int n=0;n<16;n+=4){
        float4 v = *(const float4*)(&Hprev[hb+n]);
        h[n]=v.x; h[n+1]=v.y; h[n+2]=v.z; h[n+3]=v.w;
    }
    float* ybuf = (k==0) ? ys0 : (ys123 + (long)(k-1)*SZ_BLD);

    int lg0 = seg * SEGLEN;
    int p0, stride; dir_base(k, lg0, p0, stride);
    long addr  = ((long)b*LL + p0)*DIN + d;
    long astep = (long)stride*DIN;
    __syncthreads();

    float u = xc[addr];
    for(int i=0; i<SEGLEN; i++){
        const float* row = &rows[i*XROW];
        float s = bdt;
        #pragma unroll
        for(int r=0;r<6;r++) s = fmaf(row[r], w6[r], s);
        float dt, E; dt_and_E(s, dt, E);
        float wi = dt * u;
        float unext = 0.f;
        long addrN = addr + astep;
        if(i+1 < SEGLEN) unext = xc[addrN];
        float En[16];
        if(fast){ pow_tree(E, En); }
        else {
            #pragma unroll
            for(int n=0;n<16;n++) En[n] = __expf(dt * a[n]);
        }
        float Bv[16], Cv[16];
        #pragma unroll
        for(int n=0;n<16;n+=4){
            *(float4*)(Bv+n) = *(const float4*)(row + 8 + n);
            *(float4*)(Cv+n) = *(const float4*)(row + 24 + n);
        }
        float y = Dd * u;
        #pragma unroll
        for(int n=0;n<16;n++){
            h[n] = fmaf(En[n], h[n], wi*Bv[n]);
            y = fmaf(h[n], Cv[n], y);
        }
        ybuf[addr] = y;
        addr = addrN; u = unext;
    }
}

// ---------------- Kernel G: merge + out LN + gate + out_proj + residual
__global__ __launch_bounds__(384) void kG(const float* __restrict__ ys0,
        const float* __restrict__ ys123, const float* __restrict__ z,
        const float* __restrict__ ong, const float* __restrict__ onb,
        const float* __restrict__ Wout, const float* __restrict__ ob,
        const float* __restrict__ x, float* __restrict__ out)
{
    __shared__ float yb[16*192];
    __shared__ float sc1[384], sc2[384];
    __shared__ float mu[16], rs[16];
    int t = threadIdx.x;
    long row0 = (long)blockIdx.x * 16;

    for(int q=t; q<3072; q+=384){
        long off = row0*DIN + q;
        yb[q] = ys0[off] + ys123[off] + ys123[SZ_BLD + off] + ys123[2*SZ_BLD + off];
    }
    __syncthreads();
    {
        int r = t/24, i = t%24;
        float s=0.f, ss=0.f;
        #pragma unroll
        for(int j=0;j<8;j++){ float v = yb[r*192 + i*8 + j]; s+=v; ss+=v*v; }
        sc1[t]=s; sc2[t]=ss;
        __syncthreads();
        if(t<16){
            float S=0.f, SS=0.f;
            for(int j=0;j<24;j++){ S+=sc1[t*24+j]; SS+=sc2[t*24+j]; }
            float m = S*(1.0f/192.0f);
            float var = SS*(1.0f/192.0f) - m*m;
            mu[t]=m; rs[t]=rsqrtf(var + 1e-5f);
        }
        __syncthreads();
    }
    for(int q=t; q<3072; q+=384){
        int r=q/192, dd=q%192;
        float v = (yb[q]-mu[r])*rs[r]*ong[dd] + onb[dd];
        float zz = z[row0*DIN + q];
        yb[q] = v * (zz * sigmoidf_(zz));
    }
    __syncthreads();
    int c = t % 96, rg4 = t / 96;
    float acc[4] = {0.f,0.f,0.f,0.f};
    for(int dd=0; dd<192; dd++){
        float wv = Wout[dd*96 + c];
        #pragma unroll
        for(int j=0;j<4;j++) acc[j] = fmaf(yb[(rg4*4+j)*192 + dd], wv, acc[j]);
    }
    float bv = ob[c];
    for(int j=0;j<4;j++){
        long row = row0 + rg4*4 + j;
        out[row*96 + c] = x[row*96 + c] + acc[j] + bv;
    }
}

extern "C" void kernel_launch(void* const* d_in, const int* in_sizes, int n_in,
                              void* d_out, int out_size, void* d_ws, size_t ws_size,
                              hipStream_t stream)
{
    const float* x    = (const float*)d_in[0];
    const float* lng  = (const float*)d_in[1];
    const float* lnb  = (const float*)d_in[2];
    const float* ipw  = (const float*)d_in[3];
    const float* ipb  = (const float*)d_in[4];
    const float* cw   = (const float*)d_in[5];
    const float* cb   = (const float*)d_in[6];
    const float* xpw  = (const float*)d_in[7];
    const float* dtw  = (const float*)d_in[8];
    const float* dtb  = (const float*)d_in[9];
    const float* alog = (const float*)d_in[10];
    const float* Ds   = (const float*)d_in[11];
    const float* ong  = (const float*)d_in[12];
    const float* onb  = (const float*)d_in[13];
    const float* opw  = (const float*)d_in[14];
    const float* opb  = (const float*)d_in[15];

    float* ws    = (float*)d_ws;
    float* xi    = ws + 0;          // 3,145,728 ; reused as ys0 after conv
    float* z     = ws + 3145728;    // 3,145,728
    float* xc    = ws + 6291456;    // 3,145,728
    float* xdbl  = ws + 9437184;    // 2,621,440 (B*K*L*40)
    float* ys123 = ws + 12058624;   // 9,437,184
    float* hx    = ws + 21495808;   // 6,291,456 (hend -> exclusive prefix in place)
    float* dtsum = ws + 27787264;   //   393,216
    float* ys0   = xi;
    float* out   = (float*)d_out;

    hipLaunchKernelGGL(kA,  dim3(1024),  dim3(192), 0, stream, x, lng, lnb, ipw, ipb, xi, z);
    hipLaunchKernelGGL(kB,  dim3(12288), dim3(256), 0, stream, xi, cw, cb, xc);
    hipLaunchKernelGGL(kC,  dim3(1024),  dim3(320), 0, stream, xc, xpw, xdbl);
    hipLaunchKernelGGL(kD2, dim3(2048),  dim3(192), 0, stream, xc, xdbl, alog, dtw, dtb,
                       hx, dtsum);
    hipLaunchKernelGGL(kE3, dim3(3072),  dim3(256), 0, stream, alog, dtsum, hx);
    hipLaunchKernelGGL(kF2, dim3(2048),  dim3(192), 0, stream, xc, xdbl, alog, dtw, dtb,
                       Ds, hx, ys0, ys123);
    hipLaunchKernelGGL(kG,  dim3(1024),  dim3(384), 0, stream, ys0, ys123, z, ong, onb,
                       opw, opb, x, out);
}

// Round 12
// 312.133 us; speedup vs baseline: 1.0522x; 1.0522x over previous
//
#include <hip/hip_runtime.h>
#include <math.h>

#define CC   96
#define DIN  192
#define NST  16
#define KDIR 4
#define DTR  6
#define LL   4096
#define BB   4
#define NSEG 128
#define SEGLEN 32
#define XROW 40      // padded x_dbl row: [0..5]=dt_r, [8..23]=B, [24..39]=C

#define SZ_BLD ((long)BB*LL*DIN)    // 3,145,728

__device__ __forceinline__ float sigmoidf_(float x){
    return __builtin_amdgcn_rcpf(1.0f + __expf(-x));
}
__device__ __forceinline__ int whmap(int l){ return ((l & 63) << 6) | (l >> 6); }

// base-2 softplus + decay: dt = ln(1+e^s), E = exp(-dt) = sigmoid(-s)
__device__ __forceinline__ void dt_and_E(float s, float& dt, float& E){
    const float LOG2E = 1.4426950408889634f;
    const float LN2   = 0.6931471805599453f;
    float sn  = s * LOG2E;
    float t   = __builtin_amdgcn_exp2f(-fabsf(sn));   // 2^(-|sn|) in (0,1]
    float opt = 1.0f + t;
    float r   = __builtin_amdgcn_rcpf(opt);
    E  = (s > 0.f) ? t*r : r;
    dt = LN2 * (fmaxf(sn, 0.f) + __builtin_amdgcn_logf(opt));
}
__device__ __forceinline__ void pow_tree(float E, float* En){
    En[0]=E;
    float E2=E*E;        En[1]=E2;
    En[2]=E2*E;  float E4=E2*E2; En[3]=E4;
    En[4]=E4*E;  En[5]=E4*E2;  En[6]=E4*En[2];
    float E8=E4*E4;      En[7]=E8;
    En[8]=E8*E;  En[9]=E8*E2;  En[10]=E8*En[2]; En[11]=E8*E4;
    En[12]=E8*En[4]; En[13]=E8*En[5]; En[14]=E8*En[6]; En[15]=E8*E8;
}
__device__ __forceinline__ void dir_base(int k, int lg0, int& p0, int& stride){
    switch(k & 3){
        case 0:  p0 = lg0;               stride = 1;   break;
        case 1:  p0 = whmap(lg0);        stride = 64;  break;
        case 2:  p0 = LL - 1 - lg0;      stride = -1;  break;
        default: p0 = whmap(LL-1-lg0);   stride = -64; break;
    }
}

// ---------------- Kernel T: transpose x_proj_w (k,c,d) -> (k,d,c) for coalesced reads
__global__ __launch_bounds__(256) void kT(const float* __restrict__ xw,
                                          float* __restrict__ xwt)
{
    int tid = blockIdx.x*256 + threadIdx.x;
    if(tid >= KDIR*38*192) return;
    int d  = tid % 192;
    int kc = tid / 192;                 // k*38 + c
    int k  = kc / 38, c = kc % 38;
    xwt[((long)k*192 + d)*38 + c] = xw[tid];
}

// ---------------- Kernel A: LayerNorm + in_proj GEMM (96 -> 384), 2 cols/thread
__global__ __launch_bounds__(192) void kA(const float* __restrict__ x,
        const float* __restrict__ lng, const float* __restrict__ lnb,
        const float* __restrict__ W,   const float* __restrict__ bias,
        float* __restrict__ xi, float* __restrict__ z)
{
    __shared__ float xn[16*96];
    __shared__ float sc1[192], sc2[192];
    __shared__ float mu[16], rs[16];
    int t = threadIdx.x;
    long row0 = (long)blockIdx.x * 16;

    for(int q=t; q<16*96; q+=192) xn[q] = x[row0*96 + q];
    __syncthreads();
    {   // stats: 16 rows x 12 threads, 8 elems each (2 float4 reads)
        int r = t/12, i = t%12;
        float4 v0 = *(const float4*)(&xn[r*96 + i*8]);
        float4 v1 = *(const float4*)(&xn[r*96 + i*8 + 4]);
        float s  = v0.x+v0.y+v0.z+v0.w + v1.x+v1.y+v1.z+v1.w;
        float ss = v0.x*v0.x+v0.y*v0.y+v0.z*v0.z+v0.w*v0.w
                 + v1.x*v1.x+v1.y*v1.y+v1.z*v1.z+v1.w*v1.w;
        sc1[t]=s; sc2[t]=ss;
        __syncthreads();
        if(t<16){
            float S=0.f, SS=0.f;
            for(int j=0;j<12;j++){ S+=sc1[t*12+j]; SS+=sc2[t*12+j]; }
            float m = S*(1.0f/96.0f);
            float var = SS*(1.0f/96.0f) - m*m;
            mu[t]=m; rs[t]=rsqrtf(var + 1e-6f);
        }
        __syncthreads();
    }
    for(int q=t; q<16*96; q+=192){
        int r=q/96, c=q%96;
        xn[q] = (xn[q]-mu[r])*rs[r]*lng[c] + lnb[c];
    }
    __syncthreads();

    // GEMM: thread owns cols t (-> xi) and t+192 (-> z), 16 rows
    float acc0[16], acc1[16];
    #pragma unroll
    for(int r=0;r<16;r++){ acc0[r]=0.f; acc1[r]=0.f; }
    for(int c0=0; c0<96; c0+=4){
        float4 xv[16];
        #pragma unroll
        for(int r=0;r<16;r++) xv[r] = *(const float4*)(&xn[r*96 + c0]);
        #pragma unroll
        for(int j=0;j<4;j++){
            float w0 = W[(c0+j)*384 + t];
            float w1 = W[(c0+j)*384 + t + 192];
            #pragma unroll
            for(int r=0;r<16;r++){
                float xvj = (j==0)?xv[r].x:(j==1)?xv[r].y:(j==2)?xv[r].z:xv[r].w;
                acc0[r] = fmaf(xvj, w0, acc0[r]);
                acc1[r] = fmaf(xvj, w1, acc1[r]);
            }
        }
    }
    float b0 = bias[t], b1 = bias[t+192];
    #pragma unroll
    for(int r=0;r<16;r++){
        xi[(row0+r)*DIN + t] = acc0[r] + b0;
        z [(row0+r)*DIN + t] = acc1[r] + b1;
    }
}

// ---------------- Kernel B: depthwise 3x3 conv (SAME) + bias + SiLU
__global__ __launch_bounds__(256) void kB(const float* __restrict__ xi,
        const float* __restrict__ cw, const float* __restrict__ cb,
        float* __restrict__ xc)
{
    long idx = (long)blockIdx.x*256 + threadIdx.x;
    if(idx >= SZ_BLD) return;
    int d = (int)(idx % DIN);
    long rg = idx / DIN;
    int p = (int)(rg % LL); int b = (int)(rg / LL);
    int h = p >> 6, w = p & 63;
    float acc = 0.f;
    #pragma unroll
    for(int dh=0; dh<3; dh++){
        int hh = h + dh - 1;
        if(hh < 0 || hh >= 64) continue;
        #pragma unroll
        for(int dw=0; dw<3; dw++){
            int ww2 = w + dw - 1;
            if(ww2 < 0 || ww2 >= 64) continue;
            acc = fmaf(xi[((long)b*LL + hh*64 + ww2)*DIN + d], cw[d*9 + dh*3 + dw], acc);
        }
    }
    acc += cb[d];
    xc[idx] = acc * sigmoidf_(acc);
}

// ---------------- Kernel C v3: x_proj (192 -> 38x4), broadcast LDS + coalesced W^T
// 8 rows/block, 2048 blocks; thread owns one (k,c) column, 8 rows
__global__ __launch_bounds__(192) void kC(const float* __restrict__ xc,
        const float* __restrict__ xwt, float* __restrict__ xdbl)
{
    __shared__ float ls[8*192];
    int t = threadIdx.x;
    long row0 = (long)blockIdx.x * 8;
    int b  = (int)(row0 / LL);
    int p0 = (int)(row0 % LL);
    for(int q=t; q<8*192; q+=192) ls[q] = xc[row0*DIN + q];
    __syncthreads();
    if(t < 152){
        int k = t/38, c = t%38;
        const float* wt = xwt + (long)k*192*38 + c;
        float acc[8];
        #pragma unroll
        for(int r=0;r<8;r++) acc[r]=0.f;
        for(int d=0; d<192; d+=4){
            float w0 = wt[(d+0)*38];       // consecutive lanes -> consecutive addr
            float w1 = wt[(d+1)*38];
            float w2 = wt[(d+2)*38];
            float w3 = wt[(d+3)*38];
            #pragma unroll
            for(int r=0;r<8;r++){
                float4 lv = *(const float4*)(&ls[r*192 + d]);   // wave-uniform broadcast
                acc[r] = fmaf(lv.x,w0, fmaf(lv.y,w1, fmaf(lv.z,w2, fmaf(lv.w,w3, acc[r]))));
            }
        }
        int cs = (c < 6) ? c : c + 2;   // dt at 0..5, B at 8..23, C at 24..39
        #pragma unroll
        for(int r=0;r<8;r++){
            int p = p0 + r;
            int lk;
            if(k==0) lk = p;
            else if(k==1) lk = whmap(p);
            else if(k==2) lk = LL-1-p;
            else lk = LL-1-whmap(p);
            xdbl[(((long)(b*KDIR + k)*LL + lk)*XROW) + cs] = acc[r];
        }
    }
}

// ---------------- Kernel D2: scan pass 1 — segment-local hend + dtsum ONLY
__global__ __launch_bounds__(192) void kD2(const float* __restrict__ xc,
        const float* __restrict__ xdbl, const float* __restrict__ alog,
        const float* __restrict__ dtw,  const float* __restrict__ dtb,
        float* __restrict__ hend, float* __restrict__ dtsum)
{
    __shared__ float rows[SEGLEN*XROW];
    int t = threadIdx.x;
    int blk = blockIdx.x;
    int bk = blk / NSEG, seg = blk % NSEG;
    int b = bk / KDIR, k = bk % KDIR;
    {
        const float* src = xdbl + ((long)bk*LL + seg*SEGLEN)*XROW;
        for(int q=t; q<SEGLEN*XROW; q+=192) rows[q] = src[q];
    }
    int d = t, kd = k*192 + d;
    float a[16]; bool fast = true;
    #pragma unroll
    for(int n=0;n<16;n++){
        a[n] = -__expf(alog[kd*16 + n]);
        fast = fast && (fabsf(a[n] + (float)(n+1)) < 1e-3f);
    }
    float w6[6];
    #pragma unroll
    for(int r=0;r<6;r++) w6[r] = dtw[kd*6 + r];
    float bdt = dtb[kd];

    int lg0 = seg * SEGLEN;
    int p0, stride; dir_base(k, lg0, p0, stride);
    long addr  = ((long)b*LL + p0)*DIN + d;
    long astep = (long)stride*DIN;

    float h[16];
    #pragma unroll
    for(int n=0;n<16;n++) h[n]=0.f;
    float sdt = 0.f;
    __syncthreads();

    float u = xc[addr];
    for(int i=0; i<SEGLEN; i++){
        const float* row = &rows[i*XROW];
        float s = bdt;
        #pragma unroll
        for(int r=0;r<6;r++) s = fmaf(row[r], w6[r], s);
        float dt, E; dt_and_E(s, dt, E);
        sdt += dt;
        float wi = dt * u;
        float unext = 0.f;
        long addrN = addr + astep;
        if(i+1 < SEGLEN) unext = xc[addrN];
        float En[16];
        if(fast){ pow_tree(E, En); }
        else {
            #pragma unroll
            for(int n=0;n<16;n++) En[n] = __expf(dt * a[n]);
        }
        float Bv[16];
        #pragma unroll
        for(int n=0;n<16;n+=4) *(float4*)(Bv+n) = *(const float4*)(row + 8 + n);
        #pragma unroll
        for(int n=0;n<16;n++) h[n] = fmaf(En[n], h[n], wi*Bv[n]);
        addr = addrN; u = unext;
    }
    long hb = (((long)bk*NSEG + seg)*192 + d)*16;
    #pragma unroll
    for(int n=0;n<16;n+=4)
        *(float4*)(&hend[hb+n]) = make_float4(h[n],h[n+1],h[n+2],h[n+3]);
    dtsum[((long)bk*NSEG + seg)*192 + d] = sdt;
}

// ---------------- Kernel E3: inter-segment scan, chunk-parallel + wave-shuffle
__global__ __launch_bounds__(256) void kE3(const float* __restrict__ alog,
        const float* __restrict__ dtsum, float* __restrict__ hx)
{
    int tid = blockIdx.x*256 + threadIdx.x;   // 786432 total
    int c     = tid & 15;                      // chunk id within chain
    int chain = tid >> 4;                      // 49152 chains
    int n  = chain & 15;
    int d  = (chain >> 4) % 192;
    int bk = chain / 3072;
    int k  = bk & 3;
    float an = -__expf(alog[(k*192 + d)*16 + n]);
    long sbase = (long)bk*NSEG*192  + d;          // + seg*192
    long hbase = (long)bk*NSEG*3072 + d*16 + n;   // + seg*3072
    int seg0 = c*8;

    float P[8], he[8];
    #pragma unroll
    for(int i=0;i<8;i++){
        float sd = dtsum[sbase + (long)(seg0+i)*192];
        he[i]    = hx[hbase + (long)(seg0+i)*3072];
        P[i]     = __expf(an * sd);
    }
    float Pc = 1.f, Hc = 0.f;
    #pragma unroll
    for(int i=0;i<8;i++){
        Hc = fmaf(P[i], Hc, he[i]);
        Pc *= P[i];
    }
    #pragma unroll
    for(int dist=1; dist<16; dist<<=1){
        float Pp = __shfl_up(Pc, dist, 16);
        float Hp = __shfl_up(Hc, dist, 16);
        if(c >= dist){
            Hc = fmaf(Pc, Hp, Hc);
            Pc *= Pp;
        }
    }
    float H = __shfl_up(Hc, 1, 16);
    if(c == 0) H = 0.f;
    #pragma unroll
    for(int i=0;i<8;i++){
        hx[hbase + (long)(seg0+i)*3072] = H;
        H = fmaf(P[i], H, he[i]);
    }
}

// ---------------- Kernel F2: scan pass 3 — full scan from Hprev, single ys write
__global__ __launch_bounds__(192) void kF2(const float* __restrict__ xc,
        const float* __restrict__ xdbl, const float* __restrict__ alog,
        const float* __restrict__ dtw,  const float* __restrict__ dtb,
        const float* __restrict__ Ds,   const float* __restrict__ Hprev,
        float* __restrict__ ys0, float* __restrict__ ys123)
{
    __shared__ float rows[SEGLEN*XROW];
    int t = threadIdx.x;
    int blk = blockIdx.x;
    int bk = blk / NSEG, seg = blk % NSEG;
    int b = bk / KDIR, k = bk % KDIR;
    {
        const float* src = xdbl + ((long)bk*LL + seg*SEGLEN)*XROW;
        for(int q=t; q<SEGLEN*XROW; q+=192) rows[q] = src[q];
    }
    int d = t, kd = k*192 + d;
    float a[16]; bool fast = true;
    #pragma unroll
    for(int n=0;n<16;n++){
        a[n] = -__expf(alog[kd*16 + n]);
        fast = fast && (fabsf(a[n] + (float)(n+1)) < 1e-3f);
    }
    float w6[6];
    #pragma unroll
    for(int r=0;r<6;r++) w6[r] = dtw[kd*6 + r];
    float bdt = dtb[kd];
    float Dd  = Ds[kd];
    float h[16];
    long hb = (((long)bk*NSEG + seg)*192 + d)*16;
    #pragma unroll
    for(int n=0;n<16;n+=4){
        float4 v = *(const float4*)(&Hprev[hb+n]);
        h[n]=v.x; h[n+1]=v.y; h[n+2]=v.z; h[n+3]=v.w;
    }
    float* ybuf = (k==0) ? ys0 : (ys123 + (long)(k-1)*SZ_BLD);

    int lg0 = seg * SEGLEN;
    int p0, stride; dir_base(k, lg0, p0, stride);
    long addr  = ((long)b*LL + p0)*DIN + d;
    long astep = (long)stride*DIN;
    __syncthreads();

    float u = xc[addr];
    for(int i=0; i<SEGLEN; i++){
        const float* row = &rows[i*XROW];
        float s = bdt;
        #pragma unroll
        for(int r=0;r<6;r++) s = fmaf(row[r], w6[r], s);
        float dt, E; dt_and_E(s, dt, E);
        float wi = dt * u;
        float unext = 0.f;
        long addrN = addr + astep;
        if(i+1 < SEGLEN) unext = xc[addrN];
        float En[16];
        if(fast){ pow_tree(E, En); }
        else {
            #pragma unroll
            for(int n=0;n<16;n++) En[n] = __expf(dt * a[n]);
        }
        float Bv[16], Cv[16];
        #pragma unroll
        for(int n=0;n<16;n+=4){
            *(float4*)(Bv+n) = *(const float4*)(row + 8 + n);
            *(float4*)(Cv+n) = *(const float4*)(row + 24 + n);
        }
        float y = Dd * u;
        #pragma unroll
        for(int n=0;n<16;n++){
            h[n] = fmaf(En[n], h[n], wi*Bv[n]);
            y = fmaf(h[n], Cv[n], y);
        }
        ybuf[addr] = y;
        addr = addrN; u = unext;
    }
}

// ---------------- Kernel G: merge + out LN + gate + out_proj + residual
__global__ __launch_bounds__(384) void kG(const float* __restrict__ ys0,
        const float* __restrict__ ys123, const float* __restrict__ z,
        const float* __restrict__ ong, const float* __restrict__ onb,
        const float* __restrict__ Wout, const float* __restrict__ ob,
        const float* __restrict__ x, float* __restrict__ out)
{
    __shared__ float yb[16*192];
    __shared__ float sc1[384], sc2[384];
    __shared__ float mu[16], rs[16];
    int t = threadIdx.x;
    long row0 = (long)blockIdx.x * 16;

    for(int q=t; q<3072; q+=384){
        long off = row0*DIN + q;
        yb[q] = ys0[off] + ys123[off] + ys123[SZ_BLD + off] + ys123[2*SZ_BLD + off];
    }
    __syncthreads();
    {
        int r = t/24, i = t%24;
        float s=0.f, ss=0.f;
        #pragma unroll
        for(int j=0;j<8;j++){ float v = yb[r*192 + i*8 + j]; s+=v; ss+=v*v; }
        sc1[t]=s; sc2[t]=ss;
        __syncthreads();
        if(t<16){
            float S=0.f, SS=0.f;
            for(int j=0;j<24;j++){ S+=sc1[t*24+j]; SS+=sc2[t*24+j]; }
            float m = S*(1.0f/192.0f);
            float var = SS*(1.0f/192.0f) - m*m;
            mu[t]=m; rs[t]=rsqrtf(var + 1e-5f);
        }
        __syncthreads();
    }
    for(int q=t; q<3072; q+=384){
        int r=q/192, dd=q%192;
        float v = (yb[q]-mu[r])*rs[r]*ong[dd] + onb[dd];
        float zz = z[row0*DIN + q];
        yb[q] = v * (zz * sigmoidf_(zz));
    }
    __syncthreads();
    int c = t % 96, rg4 = t / 96;
    float acc[4] = {0.f,0.f,0.f,0.f};
    for(int dd=0; dd<192; dd++){
        float wv = Wout[dd*96 + c];
        #pragma unroll
        for(int j=0;j<4;j++) acc[j] = fmaf(yb[(rg4*4+j)*192 + dd], wv, acc[j]);
    }
    float bv = ob[c];
    for(int j=0;j<4;j++){
        long row = row0 + rg4*4 + j;
        out[row*96 + c] = x[row*96 + c] + acc[j] + bv;
    }
}

extern "C" void kernel_launch(void* const* d_in, const int* in_sizes, int n_in,
                              void* d_out, int out_size, void* d_ws, size_t ws_size,
                              hipStream_t stream)
{
    const float* x    = (const float*)d_in[0];
    const float* lng  = (const float*)d_in[1];
    const float* lnb  = (const float*)d_in[2];
    const float* ipw  = (const float*)d_in[3];
    const float* ipb  = (const float*)d_in[4];
    const float* cw   = (const float*)d_in[5];
    const float* cb   = (const float*)d_in[6];
    const float* xpw  = (const float*)d_in[7];
    const float* dtw  = (const float*)d_in[8];
    const float* dtb  = (const float*)d_in[9];
    const float* alog = (const float*)d_in[10];
    const float* Ds   = (const float*)d_in[11];
    const float* ong  = (const float*)d_in[12];
    const float* onb  = (const float*)d_in[13];
    const float* opw  = (const float*)d_in[14];
    const float* opb  = (const float*)d_in[15];

    float* ws    = (float*)d_ws;
    float* xi    = ws + 0;          // 3,145,728 ; reused as ys0 after conv
    float* z     = ws + 3145728;    // 3,145,728
    float* xc    = ws + 6291456;    // 3,145,728
    float* xdbl  = ws + 9437184;    // 2,621,440 (B*K*L*40)
    float* ys123 = ws + 12058624;   // 9,437,184
    float* hx    = ws + 21495808;   // 6,291,456 (hend -> exclusive prefix in place)
    float* dtsum = ws + 27787264;   //   393,216
    float* xwt   = ws + 28180480;   //    29,184 (transposed x_proj_w)
    float* ys0   = xi;
    float* out   = (float*)d_out;

    hipLaunchKernelGGL(kT,  dim3(114),   dim3(256), 0, stream, xpw, xwt);
    hipLaunchKernelGGL(kA,  dim3(1024),  dim3(192), 0, stream, x, lng, lnb, ipw, ipb, xi, z);
    hipLaunchKernelGGL(kB,  dim3(12288), dim3(256), 0, stream, xi, cw, cb, xc);
    hipLaunchKernelGGL(kC,  dim3(2048),  dim3(192), 0, stream, xc, xwt, xdbl);
    hipLaunchKernelGGL(kD2, dim3(2048),  dim3(192), 0, stream, xc, xdbl, alog, dtw, dtb,
                       hx, dtsum);
    hipLaunchKernelGGL(kE3, dim3(3072),  dim3(256), 0, stream, alog, dtsum, hx);
    hipLaunchKernelGGL(kF2, dim3(2048),  dim3(192), 0, stream, xc, xdbl, alog, dtw, dtb,
                       Ds, hx, ys0, ys123);
    hipLaunchKernelGGL(kG,  dim3(1024),  dim3(384), 0, stream, ys0, ys123, z, ong, onb,
                       opw, opb, x, out);
}

// Round 14
// 304.188 us; speedup vs baseline: 1.0797x; 1.0261x over previous
//
#include <hip/hip_runtime.h>
#include <math.h>

#define CC   96
#define DIN  192
#define NST  16
#define KDIR 4
#define DTR  6
#define LL   4096
#define BB   4
#define NSEG 128
#define SEGLEN 32
#define XROW 40      // padded x_dbl row: [0..5]=dt_r, [8..23]=B, [24..39]=C

#define SZ_BLD ((long)BB*LL*DIN)    // 3,145,728

__device__ __forceinline__ float sigmoidf_(float x){
    return __builtin_amdgcn_rcpf(1.0f + __expf(-x));
}
__device__ __forceinline__ int whmap(int l){ return ((l & 63) << 6) | (l >> 6); }

// base-2 softplus + decay: dt = ln(1+e^s), E = exp(-dt) = sigmoid(-s)
__device__ __forceinline__ void dt_and_E(float s, float& dt, float& E){
    const float LOG2E = 1.4426950408889634f;
    const float LN2   = 0.6931471805599453f;
    float sn  = s * LOG2E;
    float t   = __builtin_amdgcn_exp2f(-fabsf(sn));   // 2^(-|sn|) in (0,1]
    float opt = 1.0f + t;
    float r   = __builtin_amdgcn_rcpf(opt);
    E  = (s > 0.f) ? t*r : r;
    dt = LN2 * (fmaxf(sn, 0.f) + __builtin_amdgcn_logf(opt));
}
__device__ __forceinline__ void pow_tree(float E, float* En){
    En[0]=E;
    float E2=E*E;        En[1]=E2;
    En[2]=E2*E;  float E4=E2*E2; En[3]=E4;
    En[4]=E4*E;  En[5]=E4*E2;  En[6]=E4*En[2];
    float E8=E4*E4;      En[7]=E8;
    En[8]=E8*E;  En[9]=E8*E2;  En[10]=E8*En[2]; En[11]=E8*E4;
    En[12]=E8*En[4]; En[13]=E8*En[5]; En[14]=E8*En[6]; En[15]=E8*E8;
}
__device__ __forceinline__ void dir_base(int k, int lg0, int& p0, int& stride){
    switch(k & 3){
        case 0:  p0 = lg0;               stride = 1;   break;
        case 1:  p0 = whmap(lg0);        stride = 64;  break;
        case 2:  p0 = LL - 1 - lg0;      stride = -1;  break;
        default: p0 = whmap(LL-1-lg0);   stride = -64; break;
    }
}

// ---------------- Kernel T v2: transpose x_proj_w (k,c,d) -> (d, k*38+c)
__global__ __launch_bounds__(256) void kT(const float* __restrict__ xw,
                                          float* __restrict__ xwt)
{
    int tid = blockIdx.x*256 + threadIdx.x;
    if(tid >= KDIR*38*192) return;
    int d  = tid % 192;
    int kc = tid / 192;                 // k*38 + c
    xwt[(long)d*152 + kc] = xw[tid];
}

// ---------------- Kernel A: LayerNorm + in_proj GEMM (96 -> 384), 2 cols/thread
__global__ __launch_bounds__(192) void kA(const float* __restrict__ x,
        const float* __restrict__ lng, const float* __restrict__ lnb,
        const float* __restrict__ W,   const float* __restrict__ bias,
        float* __restrict__ xi, float* __restrict__ z)
{
    __shared__ float xn[16*96];
    __shared__ float sc1[192], sc2[192];
    __shared__ float mu[16], rs[16];
    int t = threadIdx.x;
    long row0 = (long)blockIdx.x * 16;

    for(int q=t; q<16*96; q+=192) xn[q] = x[row0*96 + q];
    __syncthreads();
    {   // stats: 16 rows x 12 threads, 8 elems each (2 float4 reads)
        int r = t/12, i = t%12;
        float4 v0 = *(const float4*)(&xn[r*96 + i*8]);
        float4 v1 = *(const float4*)(&xn[r*96 + i*8 + 4]);
        float s  = v0.x+v0.y+v0.z+v0.w + v1.x+v1.y+v1.z+v1.w;
        float ss = v0.x*v0.x+v0.y*v0.y+v0.z*v0.z+v0.w*v0.w
                 + v1.x*v1.x+v1.y*v1.y+v1.z*v1.z+v1.w*v1.w;
        sc1[t]=s; sc2[t]=ss;
        __syncthreads();
        if(t<16){
            float S=0.f, SS=0.f;
            for(int j=0;j<12;j++){ S+=sc1[t*12+j]; SS+=sc2[t*12+j]; }
            float m = S*(1.0f/96.0f);
            float var = SS*(1.0f/96.0f) - m*m;
            mu[t]=m; rs[t]=rsqrtf(var + 1e-6f);
        }
        __syncthreads();
    }
    for(int q=t; q<16*96; q+=192){
        int r=q/96, c=q%96;
        xn[q] = (xn[q]-mu[r])*rs[r]*lng[c] + lnb[c];
    }
    __syncthreads();

    // GEMM: thread owns cols t (-> xi) and t+192 (-> z), 16 rows
    float acc0[16], acc1[16];
    #pragma unroll
    for(int r=0;r<16;r++){ acc0[r]=0.f; acc1[r]=0.f; }
    for(int c0=0; c0<96; c0+=4){
        float4 xv[16];
        #pragma unroll
        for(int r=0;r<16;r++) xv[r] = *(const float4*)(&xn[r*96 + c0]);
        #pragma unroll
        for(int j=0;j<4;j++){
            float w0 = W[(c0+j)*384 + t];
            float w1 = W[(c0+j)*384 + t + 192];
            #pragma unroll
            for(int r=0;r<16;r++){
                float xvj = (j==0)?xv[r].x:(j==1)?xv[r].y:(j==2)?xv[r].z:xv[r].w;
                acc0[r] = fmaf(xvj, w0, acc0[r]);
                acc1[r] = fmaf(xvj, w1, acc1[r]);
            }
        }
    }
    float b0 = bias[t], b1 = bias[t+192];
    #pragma unroll
    for(int r=0;r<16;r++){
        xi[(row0+r)*DIN + t] = acc0[r] + b0;
        z [(row0+r)*DIN + t] = acc1[r] + b1;
    }
}

// ---------------- Kernel B: depthwise 3x3 conv (SAME) + bias + SiLU
__global__ __launch_bounds__(256) void kB(const float* __restrict__ xi,
        const float* __restrict__ cw, const float* __restrict__ cb,
        float* __restrict__ xc)
{
    long idx = (long)blockIdx.x*256 + threadIdx.x;
    if(idx >= SZ_BLD) return;
    int d = (int)(idx % DIN);
    long rg = idx / DIN;
    int p = (int)(rg % LL); int b = (int)(rg / LL);
    int h = p >> 6, w = p & 63;
    float acc = 0.f;
    #pragma unroll
    for(int dh=0; dh<3; dh++){
        int hh = h + dh - 1;
        if(hh < 0 || hh >= 64) continue;
        #pragma unroll
        for(int dw=0; dw<3; dw++){
            int ww2 = w + dw - 1;
            if(ww2 < 0 || ww2 >= 64) continue;
            acc = fmaf(xi[((long)b*LL + hh*64 + ww2)*DIN + d], cw[d*9 + dh*3 + dw], acc);
        }
    }
    acc += cb[d];
    xc[idx] = acc * sigmoidf_(acc);
}

// ---------------- Kernel C v4: x_proj, wave = 8 rows x all 152 cols, no LDS
// 512 blocks x 256 threads (4 waves); lane owns cols {l, l+64, l+128(if l<24)}
__global__ __launch_bounds__(256) void kC(const float* __restrict__ xc,
        const float* __restrict__ xwt, float* __restrict__ xdbl)
{
    int t = threadIdx.x;
    int wave = t >> 6, l = t & 63;
    long row0 = (long)blockIdx.x * 32 + wave * 8;   // 8 rows per wave
    int b  = (int)(row0 / LL);
    int p0 = (int)(row0 % LL);
    const float* rp = xc + row0 * DIN;

    int c0 = l, c1 = 64 + l;
    bool has2 = (l < 24);
    int c2 = has2 ? (128 + l) : 0;

    float acc0[8], acc1[8], acc2[8];
    #pragma unroll
    for(int r=0;r<8;r++){ acc0[r]=0.f; acc1[r]=0.f; acc2[r]=0.f; }

    for(int d=0; d<192; d+=4){
        float w0j[4], w1j[4], w2j[4];
        #pragma unroll
        for(int j=0;j<4;j++){
            const float* wr = xwt + (long)(d+j)*152;
            w0j[j] = wr[c0];
            w1j[j] = wr[c1];
            w2j[j] = wr[c2];          // l>=24 reads col 0 (unused), no OOB
        }
        #pragma unroll
        for(int r=0;r<8;r++){
            float4 xv = *(const float4*)(rp + r*DIN + d);   // wave-uniform broadcast
            acc0[r] = fmaf(xv.x,w0j[0], fmaf(xv.y,w0j[1], fmaf(xv.z,w0j[2], fmaf(xv.w,w0j[3], acc0[r]))));
            acc1[r] = fmaf(xv.x,w1j[0], fmaf(xv.y,w1j[1], fmaf(xv.z,w1j[2], fmaf(xv.w,w1j[3], acc1[r]))));
            acc2[r] = fmaf(xv.x,w2j[0], fmaf(xv.y,w2j[1], fmaf(xv.z,w2j[2], fmaf(xv.w,w2j[3], acc2[r]))));
        }
    }

    #pragma unroll
    for(int r=0;r<8;r++){
        int p = p0 + r;
        int lk0 = p, lk1 = whmap(p);
        // col c0 and c1 and c2: cc -> k=cc/38, c=cc%38
        {
            int k = c0/38, c = c0%38;
            int cs = (c<6)? c : c+2;
            int lk = (k==0)? lk0 : (k==1)? lk1 : (k==2)? (LL-1-lk0) : (LL-1-lk1);
            xdbl[(((long)(b*KDIR + k)*LL + lk)*XROW) + cs] = acc0[r];
        }
        {
            int k = c1/38, c = c1%38;
            int cs = (c<6)? c : c+2;
            int lk = (k==0)? lk0 : (k==1)? lk1 : (k==2)? (LL-1-lk0) : (LL-1-lk1);
            xdbl[(((long)(b*KDIR + k)*LL + lk)*XROW) + cs] = acc1[r];
        }
        if(has2){
            int k = c2/38, c = c2%38;
            int cs = (c<6)? c : c+2;
            int lk = (k==0)? lk0 : (k==1)? lk1 : (k==2)? (LL-1-lk0) : (LL-1-lk1);
            xdbl[(((long)(b*KDIR + k)*LL + lk)*XROW) + cs] = acc2[r];
        }
    }
}

// ---------------- Kernel D2: scan pass 1 — segment-local hend + dtsum ONLY
__global__ __launch_bounds__(192) void kD2(const float* __restrict__ xc,
        const float* __restrict__ xdbl, const float* __restrict__ alog,
        const float* __restrict__ dtw,  const float* __restrict__ dtb,
        float* __restrict__ hend, float* __restrict__ dtsum)
{
    __shared__ float rows[SEGLEN*XROW];
    int t = threadIdx.x;
    int blk = blockIdx.x;
    int bk = blk / NSEG, seg = blk % NSEG;
    int b = bk / KDIR, k = bk % KDIR;
    {
        const float* src = xdbl + ((long)bk*LL + seg*SEGLEN)*XROW;
        for(int q=t; q<SEGLEN*XROW; q+=192) rows[q] = src[q];
    }
    int d = t, kd = k*192 + d;
    float a[16]; bool fast = true;
    #pragma unroll
    for(int n=0;n<16;n++){
        a[n] = -__expf(alog[kd*16 + n]);
        fast = fast && (fabsf(a[n] + (float)(n+1)) < 1e-3f);
    }
    float w6[6];
    #pragma unroll
    for(int r=0;r<6;r++) w6[r] = dtw[kd*6 + r];
    float bdt = dtb[kd];

    int lg0 = seg * SEGLEN;
    int p0, stride; dir_base(k, lg0, p0, stride);
    long addr  = ((long)b*LL + p0)*DIN + d;
    long astep = (long)stride*DIN;

    float h[16];
    #pragma unroll
    for(int n=0;n<16;n++) h[n]=0.f;
    float sdt = 0.f;
    __syncthreads();

    float u = xc[addr];
    for(int i=0; i<SEGLEN; i++){
        const float* row = &rows[i*XROW];
        float s = bdt;
        #pragma unroll
        for(int r=0;r<6;r++) s = fmaf(row[r], w6[r], s);
        float dt, E; dt_and_E(s, dt, E);
        sdt += dt;
        float wi = dt * u;
        float unext = 0.f;
        long addrN = addr + astep;
        if(i+1 < SEGLEN) unext = xc[addrN];
        float En[16];
        if(fast){ pow_tree(E, En); }
        else {
            #pragma unroll
            for(int n=0;n<16;n++) En[n] = __expf(dt * a[n]);
        }
        float Bv[16];
        #pragma unroll
        for(int n=0;n<16;n+=4) *(float4*)(Bv+n) = *(const float4*)(row + 8 + n);
        #pragma unroll
        for(int n=0;n<16;n++) h[n] = fmaf(En[n], h[n], wi*Bv[n]);
        addr = addrN; u = unext;
    }
    long hb = (((long)bk*NSEG + seg)*192 + d)*16;
    #pragma unroll
    for(int n=0;n<16;n+=4)
        *(float4*)(&hend[hb+n]) = make_float4(h[n],h[n+1],h[n+2],h[n+3]);
    dtsum[((long)bk*NSEG + seg)*192 + d] = sdt;
}

// ---------------- Kernel E3: inter-segment scan, chunk-parallel + wave-shuffle
__global__ __launch_bounds__(256) void kE3(const float* __restrict__ alog,
        const float* __restrict__ dtsum, float* __restrict__ hx)
{
    int tid = blockIdx.x*256 + threadIdx.x;   // 786432 total
    int c     = tid & 15;                      // chunk id within chain
    int chain = tid >> 4;                      // 49152 chains
    int n  = chain & 15;
    int d  = (chain >> 4) % 192;
    int bk = chain / 3072;
    int k  = bk & 3;
    float an = -__expf(alog[(k*192 + d)*16 + n]);
    long sbase = (long)bk*NSEG*192  + d;          // + seg*192
    long hbase = (long)bk*NSEG*3072 + d*16 + n;   // + seg*3072
    int seg0 = c*8;

    float P[8], he[8];
    #pragma unroll
    for(int i=0;i<8;i++){
        float sd = dtsum[sbase + (long)(seg0+i)*192];
        he[i]    = hx[hbase + (long)(seg0+i)*3072];
        P[i]     = __expf(an * sd);
    }
    float Pc = 1.f, Hc = 0.f;
    #pragma unroll
    for(int i=0;i<8;i++){
        Hc = fmaf(P[i], Hc, he[i]);
        Pc *= P[i];
    }
    #pragma unroll
    for(int dist=1; dist<16; dist<<=1){
        float Pp = __shfl_up(Pc, dist, 16);
        float Hp = __shfl_up(Hc, dist, 16);
        if(c >= dist){
            Hc = fmaf(Pc, Hp, Hc);
            Pc *= Pp;
        }
    }
    float H = __shfl_up(Hc, 1, 16);
    if(c == 0) H = 0.f;
    #pragma unroll
    for(int i=0;i<8;i++){
        hx[hbase + (long)(seg0+i)*3072] = H;
        H = fmaf(P[i], H, he[i]);
    }
}

// ---------------- Kernel F2: scan pass 3 — full scan from Hprev, single ys write
__global__ __launch_bounds__(192) void kF2(const float* __restrict__ xc,
        const float* __restrict__ xdbl, const float* __restrict__ alog,
        const float* __restrict__ dtw,  const float* __restrict__ dtb,
        const float* __restrict__ Ds,   const float* __restrict__ Hprev,
        float* __restrict__ ys0, float* __restrict__ ys123)
{
    __shared__ float rows[SEGLEN*XROW];
    int t = threadIdx.x;
    int blk = blockIdx.x;
    int bk = blk / NSEG, seg = blk % NSEG;
    int b = bk / KDIR, k = bk % KDIR;
    {
        const float* src = xdbl + ((long)bk*LL + seg*SEGLEN)*XROW;
        for(int q=t; q<SEGLEN*XROW; q+=192) rows[q] = src[q];
    }
    int d = t, kd = k*192 + d;
    float a[16]; bool fast = true;
    #pragma unroll
    for(int n=0;n<16;n++){
        a[n] = -__expf(alog[kd*16 + n]);
        fast = fast && (fabsf(a[n] + (float)(n+1)) < 1e-3f);
    }
    float w6[6];
    #pragma unroll
    for(int r=0;r<6;r++) w6[r] = dtw[kd*6 + r];
    float bdt = dtb[kd];
    float Dd  = Ds[kd];
    float h[16];
    long hb = (((long)bk*NSEG + seg)*192 + d)*16;
    #pragma unroll
    for(int n=0;n<16;n+=4){
        float4 v = *(const float4*)(&Hprev[hb+n]);
        h[n]=v.x; h[n+1]=v.y; h[n+2]=v.z; h[n+3]=v.w;
    }
    float* ybuf = (k==0) ? ys0 : (ys123 + (long)(k-1)*SZ_BLD);

    int lg0 = seg * SEGLEN;
    int p0, stride; dir_base(k, lg0, p0, stride);
    long addr  = ((long)b*LL + p0)*DIN + d;
    long astep = (long)stride*DIN;
    __syncthreads();

    float u = xc[addr];
    for(int i=0; i<SEGLEN; i++){
        const float* row = &rows[i*XROW];
        float s = bdt;
        #pragma unroll
        for(int r=0;r<6;r++) s = fmaf(row[r], w6[r], s);
        float dt, E; dt_and_E(s, dt, E);
        float wi = dt * u;
        float unext = 0.f;
        long addrN = addr + astep;
        if(i+1 < SEGLEN) unext = xc[addrN];
        float En[16];
        if(fast){ pow_tree(E, En); }
        else {
            #pragma unroll
            for(int n=0;n<16;n++) En[n] = __expf(dt * a[n]);
        }
        float Bv[16], Cv[16];
        #pragma unroll
        for(int n=0;n<16;n+=4){
            *(float4*)(Bv+n) = *(const float4*)(row + 8 + n);
            *(float4*)(Cv+n) = *(const float4*)(row + 24 + n);
        }
        float y = Dd * u;
        #pragma unroll
        for(int n=0;n<16;n++){
            h[n] = fmaf(En[n], h[n], wi*Bv[n]);
            y = fmaf(h[n], Cv[n], y);
        }
        ybuf[addr] = y;
        addr = addrN; u = unext;
    }
}

// ---------------- Kernel G: merge + out LN + gate + out_proj + residual
__global__ __launch_bounds__(384) void kG(const float* __restrict__ ys0,
        const float* __restrict__ ys123, const float* __restrict__ z,
        const float* __restrict__ ong, const float* __restrict__ onb,
        const float* __restrict__ Wout, const float* __restrict__ ob,
        const float* __restrict__ x, float* __restrict__ out)
{
    __shared__ float yb[16*192];
    __shared__ float sc1[384], sc2[384];
    __shared__ float mu[16], rs[16];
    int t = threadIdx.x;
    long row0 = (long)blockIdx.x * 16;

    for(int q=t; q<3072; q+=384){
        long off = row0*DIN + q;
        yb[q] = ys0[off] + ys123[off] + ys123[SZ_BLD + off] + ys123[2*SZ_BLD + off];
    }
    __syncthreads();
    {
        int r = t/24, i = t%24;
        float s=0.f, ss=0.f;
        #pragma unroll
        for(int j=0;j<8;j++){ float v = yb[r*192 + i*8 + j]; s+=v; ss+=v*v; }
        sc1[t]=s; sc2[t]=ss;
        __syncthreads();
        if(t<16){
            float S=0.f, SS=0.f;
            for(int j=0;j<24;j++){ S+=sc1[t*24+j]; SS+=sc2[t*24+j]; }
            float m = S*(1.0f/192.0f);
            float var = SS*(1.0f/192.0f) - m*m;
            mu[t]=m; rs[t]=rsqrtf(var + 1e-5f);
        }
        __syncthreads();
    }
    for(int q=t; q<3072; q+=384){
        int r=q/192, dd=q%192;
        float v = (yb[q]-mu[r])*rs[r]*ong[dd] + onb[dd];
        float zz = z[row0*DIN + q];
        yb[q] = v * (zz * sigmoidf_(zz));
    }
    __syncthreads();
    int c = t % 96, rg4 = t / 96;
    float acc[4] = {0.f,0.f,0.f,0.f};
    for(int dd=0; dd<192; dd++){
        float wv = Wout[dd*96 + c];
        #pragma unroll
        for(int j=0;j<4;j++) acc[j] = fmaf(yb[(rg4*4+j)*192 + dd], wv, acc[j]);
    }
    float bv = ob[c];
    for(int j=0;j<4;j++){
        long row = row0 + rg4*4 + j;
        out[row*96 + c] = x[row*96 + c] + acc[j] + bv;
    }
}

extern "C" void kernel_launch(void* const* d_in, const int* in_sizes, int n_in,
                              void* d_out, int out_size, void* d_ws, size_t ws_size,
                              hipStream_t stream)
{
    const float* x    = (const float*)d_in[0];
    const float* lng  = (const float*)d_in[1];
    const float* lnb  = (const float*)d_in[2];
    const float* ipw  = (const float*)d_in[3];
    const float* ipb  = (const float*)d_in[4];
    const float* cw   = (const float*)d_in[5];
    const float* cb   = (const float*)d_in[6];
    const float* xpw  = (const float*)d_in[7];
    const float* dtw  = (const float*)d_in[8];
    const float* dtb  = (const float*)d_in[9];
    const float* alog = (const float*)d_in[10];
    const float* Ds   = (const float*)d_in[11];
    const float* ong  = (const float*)d_in[12];
    const float* onb  = (const float*)d_in[13];
    const float* opw  = (const float*)d_in[14];
    const float* opb  = (const float*)d_in[15];

    float* ws    = (float*)d_ws;
    float* xi    = ws + 0;          // 3,145,728 ; reused as ys0 after conv
    float* z     = ws + 3145728;    // 3,145,728
    float* xc    = ws + 6291456;    // 3,145,728
    float* xdbl  = ws + 9437184;    // 2,621,440 (B*K*L*40)
    float* ys123 = ws + 12058624;   // 9,437,184
    float* hx    = ws + 21495808;   // 6,291,456 (hend -> exclusive prefix in place)
    float* dtsum = ws + 27787264;   //   393,216
    float* xwt   = ws + 28180480;   //    29,184 (transposed x_proj_w, [d][152])
    float* ys0   = xi;
    float* out   = (float*)d_out;

    hipLaunchKernelGGL(kT,  dim3(114),   dim3(256), 0, stream, xpw, xwt);
    hipLaunchKernelGGL(kA,  dim3(1024),  dim3(192), 0, stream, x, lng, lnb, ipw, ipb, xi, z);
    hipLaunchKernelGGL(kB,  dim3(12288), dim3(256), 0, stream, xi, cw, cb, xc);
    hipLaunchKernelGGL(kC,  dim3(512),   dim3(256), 0, stream, xc, xwt, xdbl);
    hipLaunchKernelGGL(kD2, dim3(2048),  dim3(192), 0, stream, xc, xdbl, alog, dtw, dtb,
                       hx, dtsum);
    hipLaunchKernelGGL(kE3, dim3(3072),  dim3(256), 0, stream, alog, dtsum, hx);
    hipLaunchKernelGGL(kF2, dim3(2048),  dim3(192), 0, stream, xc, xdbl, alog, dtw, dtb,
                       Ds, hx, ys0, ys123);
    hipLaunchKernelGGL(kG,  dim3(1024),  dim3(384), 0, stream, ys0, ys123, z, ong, onb,
                       opw, opb, x, out);
}